// Round 4
// baseline (1690.912 us; speedup 1.0000x reference)
//
#include <hip/hip_runtime.h>
#include <math.h>

#define K 128
#define V 50257
#define D 128
#define H 128
#define B 256
#define T 1024
#define NLB 256
#define WPB 197   // 256*197 = 50432 >= V

typedef float vf2 __attribute__((ext_vector_type(2)));

// ---- DPP wave reduces (result valid in lane 63) ----
__device__ __forceinline__ float wave_max63(float x) {
  int xi;
#define MSTEP(ctrl, rm, bm)                                                          \
  xi = __builtin_amdgcn_update_dpp(__float_as_int(x), __float_as_int(x), ctrl, rm,   \
                                   bm, false);                                       \
  x = fmaxf(x, __int_as_float(xi));
  MSTEP(0x111, 0xf, 0xf)  // row_shr:1
  MSTEP(0x112, 0xf, 0xf)  // row_shr:2
  MSTEP(0x114, 0xf, 0xe)  // row_shr:4
  MSTEP(0x118, 0xf, 0xc)  // row_shr:8
  MSTEP(0x142, 0xa, 0xf)  // row_bcast:15
  MSTEP(0x143, 0xc, 0xf)  // row_bcast:31
#undef MSTEP
  return x;
}
__device__ __forceinline__ float wave_sum63(float x) {
  int xi;
#define SSTEP(ctrl, rm, bm)                                                          \
  xi = __builtin_amdgcn_update_dpp(0, __float_as_int(x), ctrl, rm, bm, true);        \
  x = x + __int_as_float(xi);
  SSTEP(0x111, 0xf, 0xf)
  SSTEP(0x112, 0xf, 0xf)
  SSTEP(0x114, 0xf, 0xe)
  SSTEP(0x118, 0xf, 0xc)
  SSTEP(0x142, 0xa, 0xf)
  SSTEP(0x143, 0xc, 0xf)
#undef SSTEP
  return x;
}

// scoresT[w][k] = dot(tag[k], word[w]) + bias[w]; thread-per-word, tags in LDS
__global__ void __launch_bounds__(256) k_scores(const float* __restrict__ tag_w,
                                                const float* __restrict__ word_w,
                                                const float* __restrict__ word_b,
                                                float* __restrict__ scoresT) {
  __shared__ __align__(16) float tg[K][D];  // 64 KB
  int tid = threadIdx.x;
#pragma unroll
  for (int q = 0; q < 16; q++) {
    int f4 = q * 256 + tid;
    ((float4*)tg)[f4] = ((const float4*)tag_w)[f4];
  }
  __syncthreads();
  int w = blockIdx.x * 256 + tid;
  if (w >= V) return;
  float wb = word_b[w];
  float4 wreg[32];
#pragma unroll
  for (int c = 0; c < 32; c++) wreg[c] = *(const float4*)(word_w + (size_t)w * D + 4 * c);
  for (int k4 = 0; k4 < 32; k4++) {
    float4 out;
    float* op = (float*)&out;
#pragma unroll
    for (int kk = 0; kk < 4; kk++) {
      int k = k4 * 4 + kk;
      float a0 = 0, a1 = 0, a2 = 0, a3 = 0;
#pragma unroll
      for (int c = 0; c < 32; c++) {
        float4 t4 = *(const float4*)&tg[k][4 * c];
        a0 = fmaf(t4.x, wreg[c].x, a0);
        a1 = fmaf(t4.y, wreg[c].y, a1);
        a2 = fmaf(t4.z, wreg[c].z, a2);
        a3 = fmaf(t4.w, wreg[c].w, a3);
      }
      op[kk] = (a0 + a1) + (a2 + a3) + wb;
    }
    *(float4*)&scoresT[(size_t)w * K + 4 * k4] = out;
  }
}

// per-k online (max,sumexp) over a word slice
__global__ void __launch_bounds__(256) k_collse(const float* __restrict__ scoresT,
                                                float* __restrict__ pmax,
                                                float* __restrict__ psum) {
  int tid = threadIdx.x;
  int blk = blockIdx.x;
  int k = tid & 127, half = tid >> 7;
  int w0 = blk * WPB;
  int wend = min(w0 + WPB, V);
  float m = -1e30f, s = 0.f;
  for (int w = w0 + half; w < wend; w += 2) {
    float v = scoresT[(size_t)w * K + k];
    if (v > m) { s *= __expf(m - v); m = v; }
    s += __expf(v - m);
  }
  pmax[blk * 256 + tid] = m;
  psum[blk * 256 + tid] = s;
}

__global__ void k_lsefin(const float* __restrict__ pmax, const float* __restrict__ psum,
                         float* __restrict__ lse) {
  __shared__ float sm[2][K], ss[2][K];
  int tid = threadIdx.x;
  int k = tid & 127, half = tid >> 7;
  float m = -1e30f, s = 0.f;
  for (int blk = 0; blk < NLB; blk++) {
    float pm = pmax[blk * 256 + half * 128 + k];
    float pv = psum[blk * 256 + half * 128 + k];
    float nm = fmaxf(m, pm);
    s = s * __expf(m - nm) + pv * __expf(pm - nm);
    m = nm;
  }
  sm[half][k] = m;
  ss[half][k] = s;
  __syncthreads();
  if (tid < K) {
    float nm = fmaxf(sm[0][tid], sm[1][tid]);
    float st = ss[0][tid] * __expf(sm[0][tid] - nm) + ss[1][tid] * __expf(sm[1][tid] - nm);
    lse[tid] = nm + __logf(st);
  }
}

// mB[w] = max_k (score[w][k] - lse[k])
__global__ void __launch_bounds__(256) k_rowmax(const float* __restrict__ scoresT,
                                                const float* __restrict__ lse,
                                                float* __restrict__ mB) {
  __shared__ __align__(16) float ls[K];
  int tid = threadIdx.x;
  if (tid < K) ls[tid] = lse[tid];
  __syncthreads();
  int w = blockIdx.x * 256 + tid;
  if (w >= V) return;
  const float* row = scoresT + (size_t)w * K;
  float mx = -1e30f;
#pragma unroll
  for (int c = 0; c < 32; c++) {
    float4 s4 = *(const float4*)&row[4 * c];
    float4 l4 = *(const float4*)&ls[4 * c];
    mx = fmaxf(mx, fmaxf(fmaxf(s4.x - l4.x, s4.y - l4.y), fmaxf(s4.z - l4.z, s4.w - l4.w)));
  }
  mB[w] = mx;
}

// A[i][j] = softmax over j of trans logits (row-stochastic, real space)
__global__ void k_transA(const float* __restrict__ trans_w, const float* __restrict__ trans_b,
                         const float* __restrict__ trans_q, float* __restrict__ A_out) {
  __shared__ __align__(16) float qs[H];
  __shared__ float red[2];
  int i = blockIdx.x;
  int j = threadIdx.x;
  qs[j] = trans_q[j];
  __syncthreads();
  const float* wrow = trans_w + (size_t)(i * K + j) * H;
  float acc = 0.f;
#pragma unroll
  for (int h = 0; h < H; h += 4) {
    float4 w4 = *(const float4*)(wrow + h);
    float4 q4 = *(const float4*)(qs + h);
    acc += w4.x * q4.x + w4.y * q4.y + w4.z * q4.z + w4.w * q4.w;
  }
  float logit = acc + trans_b[i * K + j];
  int wid = j >> 6;
  float m = logit;
  for (int o = 32; o; o >>= 1) m = fmaxf(m, __shfl_xor(m, o, 64));
  if ((j & 63) == 0) red[wid] = m;
  __syncthreads();
  m = fmaxf(red[0], red[1]);
  __syncthreads();
  float e = __expf(logit - m);
  float s = e;
  for (int o = 32; o; o >>= 1) s += __shfl_xor(s, o, 64);
  if ((j & 63) == 0) red[wid] = s;
  __syncthreads();
  s = red[0] + red[1];
  A_out[i * K + j] = e / s;
}

__global__ void k_pi(const float* __restrict__ x, float* __restrict__ pi) {
  int j = threadIdx.x;
  __shared__ float red[2];
  float v = x[j];
  int wid = j >> 6;
  float m = v;
  for (int o = 32; o; o >>= 1) m = fmaxf(m, __shfl_xor(m, o, 64));
  if ((j & 63) == 0) red[wid] = m;
  __syncthreads();
  m = fmaxf(red[0], red[1]);
  __syncthreads();
  float e = __expf(v - m);
  float s = e;
  for (int o = 32; o; o >>= 1) s += __shfl_xor(s, o, 64);
  if ((j & 63) == 0) red[wid] = s;
  __syncthreads();
  s = red[0] + red[1];
  pi[j] = e / (red[0] + red[1]);
}

// single-wave forward recurrence; normalized real space; no barriers in the T-loop
__global__ void __launch_bounds__(64, 1) k_forward(
    const int* __restrict__ emis, const float* __restrict__ scoresT,
    const float* __restrict__ lse, const float* __restrict__ mB,
    const float* __restrict__ A, const float* __restrict__ pi,
    float* __restrict__ sll) {
  __shared__ __align__(16) float ps[K];
  __shared__ int es[T];
  int b = blockIdx.x;
  int l = threadIdx.x;  // 0..63, owns states 2l, 2l+1
  for (int t = l; t < T; t += 64) es[t] = emis[b * T + t];
  vf2 Areg[128];
#pragma unroll
  for (int i = 0; i < 128; i++) Areg[i] = *(const vf2*)(A + i * K + 2 * l);
  vf2 lse2 = *(const vf2*)(lse + 2 * l);
  vf2 pi2 = *(const vf2*)(pi + 2 * l);
  __syncthreads();
  // prologue: p0 = pi * exp(s - lse - mB[w0]);  max(p0) >= 1/128 (ebA hits 1 somewhere)
  int w0 = es[0];
  vf2 sc0 = *(const vf2*)(scoresT + (size_t)w0 * K + 2 * l);
  float mb0 = mB[w0];
  vf2 p;
  p.x = pi2.x * __expf(sc0.x - lse2.x - mb0);
  p.y = pi2.y * __expf(sc0.y - lse2.y - mb0);
  *(vf2*)&ps[2 * l] = p;
  float Cacc = mb0;
  float zm0 = wave_max63(fmaxf(p.x, p.y));
  float z = __int_as_float(__builtin_amdgcn_readlane(__float_as_int(zm0), 63));
  z = fmaxf(z, 1e-30f);
  float r = 1.0f / z;
  float lzp = __logf(z);
  // exp pipeline, 3-deep: ebA ready for t=1; raw for t+1, t+2; index for t+3
  vf2 sc1 = *(const vf2*)(scoresT + (size_t)es[1] * K + 2 * l);
  float mbA = mB[es[1]];
  vf2 ebA;
  ebA.x = __expf(sc1.x - lse2.x - mbA);
  ebA.y = __expf(sc1.y - lse2.y - mbA);
  vf2 scB = *(const vf2*)(scoresT + (size_t)es[2] * K + 2 * l);
  float mbB = mB[es[2]];
  vf2 scC = *(const vf2*)(scoresT + (size_t)es[3] * K + 2 * l);
  float mbC = mB[es[3]];
  int wD = es[4];
  vf2 pn = p;
  for (int t = 1; t < T; t++) {
    // issue loads for word_{t+3}
    vf2 scD = *(const vf2*)(scoresT + (size_t)wD * K + 2 * l);
    float mbD = mB[wD];
    int wE = es[(t + 4 < T) ? t + 4 : T - 1];
    // matvec: q_j = sum_i ps_i * A_ij  (uniform-broadcast LDS reads, packed FMAs)
    vf2 a0 = 0, a1 = 0, a2 = 0, a3 = 0;
#pragma unroll
    for (int ii = 0; ii < 32; ii++) {
      float4 p4 = *(const float4*)&ps[4 * ii];
      a0 = __builtin_elementwise_fma((vf2){p4.x, p4.x}, Areg[4 * ii + 0], a0);
      a1 = __builtin_elementwise_fma((vf2){p4.y, p4.y}, Areg[4 * ii + 1], a1);
      a2 = __builtin_elementwise_fma((vf2){p4.z, p4.z}, Areg[4 * ii + 2], a2);
      a3 = __builtin_elementwise_fma((vf2){p4.w, p4.w}, Areg[4 * ii + 3], a3);
    }
    vf2 q = (a0 + a1) + (a2 + a3);
    pn = q * ebA;
    pn.x *= r;
    pn.y *= r;
    Cacc += lzp + mbA;
    *(vf2*)&ps[2 * l] = pn;
    // measure max(pn) -> rescale factors for NEXT step (full iteration of slack)
    float zm = wave_max63(fmaxf(pn.x, pn.y));
    z = __int_as_float(__builtin_amdgcn_readlane(__float_as_int(zm), 63));
    z = fmaxf(z, 1e-30f);
    r = 1.0f / z;
    lzp = __logf(z);
    // advance exp pipeline
    ebA.x = __expf(scB.x - lse2.x - mbB);
    ebA.y = __expf(scB.y - lse2.y - mbB);
    mbA = mbB;
    scB = scC; mbB = mbC;
    scC = scD; mbC = mbD;
    wD = wE;
  }
  float ssum = wave_sum63(pn.x + pn.y);
  if (l == 63) sll[b] = Cacc + __logf(ssum);
}

__global__ void k_loss(const float* __restrict__ sll, float* __restrict__ out) {
  int tid = threadIdx.x;
  __shared__ float red[4];
  float v = sll[tid];
#pragma unroll
  for (int o = 32; o; o >>= 1) v += __shfl_xor(v, o, 64);
  if ((tid & 63) == 0) red[tid >> 6] = v;
  __syncthreads();
  if (tid == 0) out[0] = -(red[0] + red[1] + red[2] + red[3]) / (float)B;
}

extern "C" void kernel_launch(void* const* d_in, const int* in_sizes, int n_in,
                              void* d_out, int out_size, void* d_ws, size_t ws_size,
                              hipStream_t stream) {
  const int*   emis   = (const int*)d_in[0];
  const float* initl  = (const float*)d_in[1];
  const float* tagw   = (const float*)d_in[2];
  const float* wordw  = (const float*)d_in[3];
  const float* wordb  = (const float*)d_in[4];
  const float* transw = (const float*)d_in[5];
  const float* transb = (const float*)d_in[6];
  const float* transq = (const float*)d_in[7];
  float* ws = (float*)d_ws;
  size_t off = 0;
  float* scoresT = ws + off; off += (size_t)V * K;
  float* Amat    = ws + off; off += (size_t)K * K;
  float* pivec   = ws + off; off += K;
  float* lse     = ws + off; off += K;
  float* pmax    = ws + off; off += (size_t)NLB * 256;
  float* psum    = ws + off; off += (size_t)NLB * 256;
  float* mB      = ws + off; off += (size_t)V + 64;
  float* sll     = ws + off; off += B;
  float* out = (float*)d_out;

  hipLaunchKernelGGL(k_transA, dim3(K), dim3(K), 0, stream, transw, transb, transq, Amat);
  hipLaunchKernelGGL(k_pi, dim3(1), dim3(K), 0, stream, initl, pivec);
  hipLaunchKernelGGL(k_scores, dim3((V + 255) / 256), dim3(256), 0, stream, tagw, wordw, wordb, scoresT);
  hipLaunchKernelGGL(k_collse, dim3(NLB), dim3(256), 0, stream, scoresT, pmax, psum);
  hipLaunchKernelGGL(k_lsefin, dim3(1), dim3(256), 0, stream, pmax, psum, lse);
  hipLaunchKernelGGL(k_rowmax, dim3((V + 255) / 256), dim3(256), 0, stream, scoresT, lse, mB);
  hipLaunchKernelGGL(k_forward, dim3(B), dim3(64), 0, stream, emis, scoresT, lse, mB, Amat, pivec, sll);
  hipLaunchKernelGGL(k_loss, dim3(1), dim3(256), 0, stream, sll, out);
}

// Round 5
// 1029.391 us; speedup vs baseline: 1.6426x; 1.6426x over previous
//
#include <hip/hip_runtime.h>
#include <math.h>

#define K 128
#define V 50257
#define D 128
#define H 128
#define B 256
#define T 1024
#define NLB 256
#define WPB 197   // 256*197 = 50432 >= V

typedef float f32x16 __attribute__((ext_vector_type(16)));

// ---- DPP wave reduces (result valid in lane 63) ----
__device__ __forceinline__ float wave_max63(float x) {
  int xi;
#define MSTEP(ctrl, rm, bm)                                                          \
  xi = __builtin_amdgcn_update_dpp(__float_as_int(x), __float_as_int(x), ctrl, rm,   \
                                   bm, false);                                       \
  x = fmaxf(x, __int_as_float(xi));
  MSTEP(0x111, 0xf, 0xf)  // row_shr:1
  MSTEP(0x112, 0xf, 0xf)  // row_shr:2
  MSTEP(0x114, 0xf, 0xe)  // row_shr:4
  MSTEP(0x118, 0xf, 0xc)  // row_shr:8
  MSTEP(0x142, 0xa, 0xf)  // row_bcast:15
  MSTEP(0x143, 0xc, 0xf)  // row_bcast:31
#undef MSTEP
  return x;
}
__device__ __forceinline__ float wave_sum63(float x) {
  int xi;
#define SSTEP(ctrl, rm, bm)                                                          \
  xi = __builtin_amdgcn_update_dpp(0, __float_as_int(x), ctrl, rm, bm, true);        \
  x = x + __int_as_float(xi);
  SSTEP(0x111, 0xf, 0xf)
  SSTEP(0x112, 0xf, 0xf)
  SSTEP(0x114, 0xf, 0xe)
  SSTEP(0x118, 0xf, 0xc)
  SSTEP(0x142, 0xa, 0xf)
  SSTEP(0x143, 0xc, 0xf)
#undef SSTEP
  return x;
}

// scoresT[w][k] = dot(tag[k], word[w]) + bias[w]; thread-per-word, tags in LDS
__global__ void __launch_bounds__(256) k_scores(const float* __restrict__ tag_w,
                                                const float* __restrict__ word_w,
                                                const float* __restrict__ word_b,
                                                float* __restrict__ scoresT) {
  __shared__ __align__(16) float tg[K][D];  // 64 KB
  int tid = threadIdx.x;
#pragma unroll
  for (int q = 0; q < 16; q++) {
    int f4 = q * 256 + tid;
    ((float4*)tg)[f4] = ((const float4*)tag_w)[f4];
  }
  __syncthreads();
  int w = blockIdx.x * 256 + tid;
  if (w >= V) return;
  float wb = word_b[w];
  float4 wreg[32];
#pragma unroll
  for (int c = 0; c < 32; c++) wreg[c] = *(const float4*)(word_w + (size_t)w * D + 4 * c);
  for (int k4 = 0; k4 < 32; k4++) {
    float4 out;
    float* op = (float*)&out;
#pragma unroll
    for (int kk = 0; kk < 4; kk++) {
      int k = k4 * 4 + kk;
      float a0 = 0, a1 = 0, a2 = 0, a3 = 0;
#pragma unroll
      for (int c = 0; c < 32; c++) {
        float4 t4 = *(const float4*)&tg[k][4 * c];
        a0 = fmaf(t4.x, wreg[c].x, a0);
        a1 = fmaf(t4.y, wreg[c].y, a1);
        a2 = fmaf(t4.z, wreg[c].z, a2);
        a3 = fmaf(t4.w, wreg[c].w, a3);
      }
      op[kk] = (a0 + a1) + (a2 + a3) + wb;
    }
    *(float4*)&scoresT[(size_t)w * K + 4 * k4] = out;
  }
}

// per-k online (max,sumexp) over a word slice
__global__ void __launch_bounds__(256) k_collse(const float* __restrict__ scoresT,
                                                float* __restrict__ pmax,
                                                float* __restrict__ psum) {
  int tid = threadIdx.x;
  int blk = blockIdx.x;
  int k = tid & 127, half = tid >> 7;
  int w0 = blk * WPB;
  int wend = min(w0 + WPB, V);
  float m = -1e30f, s = 0.f;
  for (int w = w0 + half; w < wend; w += 2) {
    float v = scoresT[(size_t)w * K + k];
    if (v > m) { s *= __expf(m - v); m = v; }
    s += __expf(v - m);
  }
  pmax[blk * 256 + tid] = m;
  psum[blk * 256 + tid] = s;
}

__global__ void k_lsefin(const float* __restrict__ pmax, const float* __restrict__ psum,
                         float* __restrict__ lse) {
  __shared__ float sm[2][K], ss[2][K];
  int tid = threadIdx.x;
  int k = tid & 127, half = tid >> 7;
  float m = -1e30f, s = 0.f;
  for (int blk = 0; blk < NLB; blk++) {
    float pm = pmax[blk * 256 + half * 128 + k];
    float pv = psum[blk * 256 + half * 128 + k];
    float nm = fmaxf(m, pm);
    s = s * __expf(m - nm) + pv * __expf(pm - nm);
    m = nm;
  }
  sm[half][k] = m;
  ss[half][k] = s;
  __syncthreads();
  if (tid < K) {
    float nm = fmaxf(sm[0][tid], sm[1][tid]);
    float st = ss[0][tid] * __expf(sm[0][tid] - nm) + ss[1][tid] * __expf(sm[1][tid] - nm);
    lse[tid] = nm + __logf(st);
  }
}

// mB[w] = max_k (score[w][k] - lse[k])
__global__ void __launch_bounds__(256) k_rowmax(const float* __restrict__ scoresT,
                                                const float* __restrict__ lse,
                                                float* __restrict__ mB) {
  __shared__ __align__(16) float ls[K];
  int tid = threadIdx.x;
  if (tid < K) ls[tid] = lse[tid];
  __syncthreads();
  int w = blockIdx.x * 256 + tid;
  if (w >= V) return;
  const float* row = scoresT + (size_t)w * K;
  float mx = -1e30f;
#pragma unroll
  for (int c = 0; c < 32; c++) {
    float4 s4 = *(const float4*)&row[4 * c];
    float4 l4 = *(const float4*)&ls[4 * c];
    mx = fmaxf(mx, fmaxf(fmaxf(s4.x - l4.x, s4.y - l4.y), fmaxf(s4.z - l4.z, s4.w - l4.w)));
  }
  mB[w] = mx;
}

// Acol[j][i] = softmax over j of row i (column-major so k_forward loads a column contiguously)
__global__ void k_transA(const float* __restrict__ trans_w, const float* __restrict__ trans_b,
                         const float* __restrict__ trans_q, float* __restrict__ Acol) {
  __shared__ __align__(16) float qs[H];
  __shared__ float red[2];
  int i = blockIdx.x;
  int j = threadIdx.x;
  qs[j] = trans_q[j];
  __syncthreads();
  const float* wrow = trans_w + (size_t)(i * K + j) * H;
  float acc = 0.f;
#pragma unroll
  for (int h = 0; h < H; h += 4) {
    float4 w4 = *(const float4*)(wrow + h);
    float4 q4 = *(const float4*)(qs + h);
    acc += w4.x * q4.x + w4.y * q4.y + w4.z * q4.z + w4.w * q4.w;
  }
  float logit = acc + trans_b[i * K + j];
  int wid = j >> 6;
  float m = logit;
  for (int o = 32; o; o >>= 1) m = fmaxf(m, __shfl_xor(m, o, 64));
  if ((j & 63) == 0) red[wid] = m;
  __syncthreads();
  m = fmaxf(red[0], red[1]);
  __syncthreads();
  float e = __expf(logit - m);
  float s = e;
  for (int o = 32; o; o >>= 1) s += __shfl_xor(s, o, 64);
  if ((j & 63) == 0) red[wid] = s;
  __syncthreads();
  s = red[0] + red[1];
  Acol[(size_t)j * K + i] = e / s;  // column-major
}

__global__ void k_pi(const float* __restrict__ x, float* __restrict__ pi) {
  int j = threadIdx.x;
  __shared__ float red[2];
  float v = x[j];
  int wid = j >> 6;
  float m = v;
  for (int o = 32; o; o >>= 1) m = fmaxf(m, __shfl_xor(m, o, 64));
  if ((j & 63) == 0) red[wid] = m;
  __syncthreads();
  m = fmaxf(red[0], red[1]);
  __syncthreads();
  float e = __expf(v - m);
  float s = e;
  for (int o = 32; o; o >>= 1) s += __shfl_xor(s, o, 64);
  if ((j & 63) == 0) red[wid] = s;
  __syncthreads();
  s = red[0] + red[1];
  pi[j] = e / (red[0] + red[1]);
}

// 2-wave forward recurrence; A column register-resident as 8 named f32x16;
// one barrier per step via double-buffered p in LDS.
__global__ void __launch_bounds__(128, 1) k_forward(
    const int* __restrict__ emis, const float* __restrict__ scoresT,
    const float* __restrict__ lse, const float* __restrict__ mB,
    const float* __restrict__ Acol, const float* __restrict__ pi,
    float* __restrict__ sll) {
  __shared__ __align__(16) float ps[2][K];
  __shared__ float zbuf[2][2];
  __shared__ float spb[2];
  __shared__ int es[T];
  int b = blockIdx.x;
  int tid = threadIdx.x;  // 0..127
  int w = tid >> 6;       // wave id
  int l = tid & 63;
  int j = tid;            // owned state column
  for (int t = tid; t < T; t += 128) es[t] = emis[b * T + t];
  const float* cp = Acol + (size_t)j * K;
  f32x16 A0 = *(const f32x16*)(cp + 0);
  f32x16 A1 = *(const f32x16*)(cp + 16);
  f32x16 A2 = *(const f32x16*)(cp + 32);
  f32x16 A3 = *(const f32x16*)(cp + 48);
  f32x16 A4 = *(const f32x16*)(cp + 64);
  f32x16 A5 = *(const f32x16*)(cp + 80);
  f32x16 A6 = *(const f32x16*)(cp + 96);
  f32x16 A7 = *(const f32x16*)(cp + 112);
  float lsej = lse[j];
  float pij = pi[j];
  __syncthreads();  // es ready
  // prologue: p0 = pi * exp(s - lse - mB[w0]); max(p0) in [1/128, 1]
  int w0 = es[0];
  float sc0 = scoresT[(size_t)w0 * K + j];
  float mb0 = mB[w0];
  float p = pij * __expf(sc0 - lsej - mb0);
  ps[0][j] = p;
  float zm0 = wave_max63(p);
  if (l == 63) zbuf[0][w] = zm0;
  float Cacc = mb0;
  // emission pipeline (4-deep)
  float scA = scoresT[(size_t)es[1] * K + j];
  float mbA = mB[es[1]];
  float ebA = __expf(scA - lsej - mbA);
  float scB = scoresT[(size_t)es[2] * K + j];
  float mbB = mB[es[2]];
  float scC = scoresT[(size_t)es[3] * K + j];
  float mbC = mB[es[3]];
  int wD = es[4];
  __syncthreads();  // ps[0], zbuf[0] visible
  float pn = p;
  for (int t = 1; t < T; t++) {
    int cur = (t - 1) & 1, nxt = t & 1;
    // prefetch token t+3
    float scD = scoresT[(size_t)wD * K + j];
    float mbD = mB[wD];
    int wE = es[(t + 4 < T) ? t + 4 : T - 1];
    // rescale factors from previous step's published max (one-step slack)
    float z = fmaxf(fmaxf(zbuf[cur][0], zbuf[cur][1]), 1e-30f);
    float r = 1.0f / z;
    float lzp = __logf(z);
    // matvec: q_j = sum_i ps[i] * A[i][j]  (broadcast LDS reads, scalar FMAs)
    float q0 = 0.f, q1 = 0.f, q2 = 0.f, q3 = 0.f;
    const float* pp = ps[cur];
#define BLK(BI, AV)                                                         \
    {                                                                       \
      float4 pa = *(const float4*)(pp + BI * 16 + 0);                       \
      float4 pb = *(const float4*)(pp + BI * 16 + 4);                       \
      float4 pc = *(const float4*)(pp + BI * 16 + 8);                       \
      float4 pd = *(const float4*)(pp + BI * 16 + 12);                      \
      q0 = fmaf(pa.x, AV[0], q0);  q1 = fmaf(pa.y, AV[1], q1);              \
      q2 = fmaf(pa.z, AV[2], q2);  q3 = fmaf(pa.w, AV[3], q3);              \
      q0 = fmaf(pb.x, AV[4], q0);  q1 = fmaf(pb.y, AV[5], q1);              \
      q2 = fmaf(pb.z, AV[6], q2);  q3 = fmaf(pb.w, AV[7], q3);              \
      q0 = fmaf(pc.x, AV[8], q0);  q1 = fmaf(pc.y, AV[9], q1);              \
      q2 = fmaf(pc.z, AV[10], q2); q3 = fmaf(pc.w, AV[11], q3);             \
      q0 = fmaf(pd.x, AV[12], q0); q1 = fmaf(pd.y, AV[13], q1);             \
      q2 = fmaf(pd.z, AV[14], q2); q3 = fmaf(pd.w, AV[15], q3);             \
    }
    BLK(0, A0) BLK(1, A1) BLK(2, A2) BLK(3, A3)
    BLK(4, A4) BLK(5, A5) BLK(6, A6) BLK(7, A7)
#undef BLK
    float q = (q0 + q1) + (q2 + q3);
    pn = q * ebA * r;
    Cacc += lzp + mbA;
    ps[nxt][j] = pn;
    float zm = wave_max63(pn);
    if (l == 63) zbuf[nxt][w] = zm;
    // advance emission pipeline
    ebA = __expf(scB - lsej - mbB);
    mbA = mbB;
    scB = scC; mbB = mbC;
    scC = scD; mbC = mbD;
    wD = wE;
    __syncthreads();
  }
  // seq_ll = Cacc + log(sum_j p_T[j])
  float sw = wave_sum63(pn);
  if (l == 63) spb[w] = sw;
  __syncthreads();
  if (tid == 0) sll[b] = Cacc + __logf(spb[0] + spb[1]);
}

__global__ void k_loss(const float* __restrict__ sll, float* __restrict__ out) {
  int tid = threadIdx.x;
  __shared__ float red[4];
  float v = sll[tid];
#pragma unroll
  for (int o = 32; o; o >>= 1) v += __shfl_xor(v, o, 64);
  if ((tid & 63) == 0) red[tid >> 6] = v;
  __syncthreads();
  if (tid == 0) out[0] = -(red[0] + red[1] + red[2] + red[3]) / (float)B;
}

extern "C" void kernel_launch(void* const* d_in, const int* in_sizes, int n_in,
                              void* d_out, int out_size, void* d_ws, size_t ws_size,
                              hipStream_t stream) {
  const int*   emis   = (const int*)d_in[0];
  const float* initl  = (const float*)d_in[1];
  const float* tagw   = (const float*)d_in[2];
  const float* wordw  = (const float*)d_in[3];
  const float* wordb  = (const float*)d_in[4];
  const float* transw = (const float*)d_in[5];
  const float* transb = (const float*)d_in[6];
  const float* transq = (const float*)d_in[7];
  float* ws = (float*)d_ws;
  size_t off = 0;
  float* scoresT = ws + off; off += (size_t)V * K;
  float* Acol    = ws + off; off += (size_t)K * K;
  float* pivec   = ws + off; off += K;
  float* lse     = ws + off; off += K;
  float* pmax    = ws + off; off += (size_t)NLB * 256;
  float* psum    = ws + off; off += (size_t)NLB * 256;
  float* mB      = ws + off; off += (size_t)V + 64;
  float* sll     = ws + off; off += B;
  float* out = (float*)d_out;

  hipLaunchKernelGGL(k_transA, dim3(K), dim3(K), 0, stream, transw, transb, transq, Acol);
  hipLaunchKernelGGL(k_pi, dim3(1), dim3(K), 0, stream, initl, pivec);
  hipLaunchKernelGGL(k_scores, dim3((V + 255) / 256), dim3(256), 0, stream, tagw, wordw, wordb, scoresT);
  hipLaunchKernelGGL(k_collse, dim3(NLB), dim3(256), 0, stream, scoresT, pmax, psum);
  hipLaunchKernelGGL(k_lsefin, dim3(1), dim3(256), 0, stream, pmax, psum, lse);
  hipLaunchKernelGGL(k_rowmax, dim3((V + 255) / 256), dim3(256), 0, stream, scoresT, lse, mB);
  hipLaunchKernelGGL(k_forward, dim3(B), dim3(128), 0, stream, emis, scoresT, lse, mB, Acol, pivec, sll);
  hipLaunchKernelGGL(k_loss, dim3(1), dim3(256), 0, stream, sll, out);
}

// Round 7
// 1021.911 us; speedup vs baseline: 1.6547x; 1.0073x over previous
//
#include <hip/hip_runtime.h>
#include <math.h>

#define K 128
#define V 50257
#define D 128
#define H 128
#define B 256
#define T 1024
#define NLB 256
#define WPB 197   // 256*197 = 50432 >= V

typedef _Float16 h2 __attribute__((ext_vector_type(2)));

__device__ __forceinline__ h2 h2cast(unsigned int u) { return __builtin_bit_cast(h2, u); }

// ---- DPP wave reduces (result valid in lane 63) ----
__device__ __forceinline__ float wave_max63(float x) {
  int xi;
#define MSTEP(ctrl, rm, bm)                                                          \
  xi = __builtin_amdgcn_update_dpp(__float_as_int(x), __float_as_int(x), ctrl, rm,   \
                                   bm, false);                                       \
  x = fmaxf(x, __int_as_float(xi));
  MSTEP(0x111, 0xf, 0xf)  // row_shr:1
  MSTEP(0x112, 0xf, 0xf)  // row_shr:2
  MSTEP(0x114, 0xf, 0xe)  // row_shr:4
  MSTEP(0x118, 0xf, 0xc)  // row_shr:8
  MSTEP(0x142, 0xa, 0xf)  // row_bcast:15
  MSTEP(0x143, 0xc, 0xf)  // row_bcast:31
#undef MSTEP
  return x;
}
__device__ __forceinline__ float wave_sum63(float x) {
  int xi;
#define SSTEP(ctrl, rm, bm)                                                          \
  xi = __builtin_amdgcn_update_dpp(0, __float_as_int(x), ctrl, rm, bm, true);        \
  x = x + __int_as_float(xi);
  SSTEP(0x111, 0xf, 0xf)
  SSTEP(0x112, 0xf, 0xf)
  SSTEP(0x114, 0xf, 0xe)
  SSTEP(0x118, 0xf, 0xc)
  SSTEP(0x142, 0xa, 0xf)
  SSTEP(0x143, 0xc, 0xf)
#undef SSTEP
  return x;
}

// scoresT[w][k] = dot(tag[k], word[w]) + bias[w]; thread-per-word, tags in LDS
__global__ void __launch_bounds__(256) k_scores(const float* __restrict__ tag_w,
                                                const float* __restrict__ word_w,
                                                const float* __restrict__ word_b,
                                                float* __restrict__ scoresT) {
  __shared__ __align__(16) float tg[K][D];  // 64 KB
  int tid = threadIdx.x;
#pragma unroll
  for (int q = 0; q < 16; q++) {
    int f4 = q * 256 + tid;
    ((float4*)tg)[f4] = ((const float4*)tag_w)[f4];
  }
  __syncthreads();
  int w = blockIdx.x * 256 + tid;
  if (w >= V) return;
  float wb = word_b[w];
  float4 wreg[32];
#pragma unroll
  for (int c = 0; c < 32; c++) wreg[c] = *(const float4*)(word_w + (size_t)w * D + 4 * c);
  for (int k4 = 0; k4 < 32; k4++) {
    float4 out;
    float* op = (float*)&out;
#pragma unroll
    for (int kk = 0; kk < 4; kk++) {
      int k = k4 * 4 + kk;
      float a0 = 0, a1 = 0, a2 = 0, a3 = 0;
#pragma unroll
      for (int c = 0; c < 32; c++) {
        float4 t4 = *(const float4*)&tg[k][4 * c];
        a0 = fmaf(t4.x, wreg[c].x, a0);
        a1 = fmaf(t4.y, wreg[c].y, a1);
        a2 = fmaf(t4.z, wreg[c].z, a2);
        a3 = fmaf(t4.w, wreg[c].w, a3);
      }
      op[kk] = (a0 + a1) + (a2 + a3) + wb;
    }
    *(float4*)&scoresT[(size_t)w * K + 4 * k4] = out;
  }
}

// per-k online (max,sumexp) over a word slice
__global__ void __launch_bounds__(256) k_collse(const float* __restrict__ scoresT,
                                                float* __restrict__ pmax,
                                                float* __restrict__ psum) {
  int tid = threadIdx.x;
  int blk = blockIdx.x;
  int k = tid & 127, half = tid >> 7;
  int w0 = blk * WPB;
  int wend = min(w0 + WPB, V);
  float m = -1e30f, s = 0.f;
  for (int w = w0 + half; w < wend; w += 2) {
    float v = scoresT[(size_t)w * K + k];
    if (v > m) { s *= __expf(m - v); m = v; }
    s += __expf(v - m);
  }
  pmax[blk * 256 + tid] = m;
  psum[blk * 256 + tid] = s;
}

__global__ void k_lsefin(const float* __restrict__ pmax, const float* __restrict__ psum,
                         float* __restrict__ lse) {
  __shared__ float sm[2][K], ss[2][K];
  int tid = threadIdx.x;
  int k = tid & 127, half = tid >> 7;
  float m = -1e30f, s = 0.f;
  for (int blk = 0; blk < NLB; blk++) {
    float pm = pmax[blk * 256 + half * 128 + k];
    float pv = psum[blk * 256 + half * 128 + k];
    float nm = fmaxf(m, pm);
    s = s * __expf(m - nm) + pv * __expf(pm - nm);
    m = nm;
  }
  sm[half][k] = m;
  ss[half][k] = s;
  __syncthreads();
  if (tid < K) {
    float nm = fmaxf(sm[0][tid], sm[1][tid]);
    float st = ss[0][tid] * __expf(sm[0][tid] - nm) + ss[1][tid] * __expf(sm[1][tid] - nm);
    lse[tid] = nm + __logf(st);
  }
}

// mB[w] = max_k (score[w][k] - lse[k])
__global__ void __launch_bounds__(256) k_rowmax(const float* __restrict__ scoresT,
                                                const float* __restrict__ lse,
                                                float* __restrict__ mB) {
  __shared__ __align__(16) float ls[K];
  int tid = threadIdx.x;
  if (tid < K) ls[tid] = lse[tid];
  __syncthreads();
  int w = blockIdx.x * 256 + tid;
  if (w >= V) return;
  const float* row = scoresT + (size_t)w * K;
  float mx = -1e30f;
#pragma unroll
  for (int c = 0; c < 32; c++) {
    float4 s4 = *(const float4*)&row[4 * c];
    float4 l4 = *(const float4*)&ls[4 * c];
    mx = fmaxf(mx, fmaxf(fmaxf(s4.x - l4.x, s4.y - l4.y), fmaxf(s4.z - l4.z, s4.w - l4.w)));
  }
  mB[w] = mx;
}

// Ah[j][i] (column-major, f16): softmax over j of row i
__global__ void k_transA(const float* __restrict__ trans_w, const float* __restrict__ trans_b,
                         const float* __restrict__ trans_q, _Float16* __restrict__ Ah) {
  __shared__ __align__(16) float qs[H];
  __shared__ float red[2];
  int i = blockIdx.x;
  int j = threadIdx.x;
  qs[j] = trans_q[j];
  __syncthreads();
  const float* wrow = trans_w + (size_t)(i * K + j) * H;
  float acc = 0.f;
#pragma unroll
  for (int h = 0; h < H; h += 4) {
    float4 w4 = *(const float4*)(wrow + h);
    float4 q4 = *(const float4*)(qs + h);
    acc += w4.x * q4.x + w4.y * q4.y + w4.z * q4.z + w4.w * q4.w;
  }
  float logit = acc + trans_b[i * K + j];
  int wid = j >> 6;
  float m = logit;
  for (int o = 32; o; o >>= 1) m = fmaxf(m, __shfl_xor(m, o, 64));
  if ((j & 63) == 0) red[wid] = m;
  __syncthreads();
  m = fmaxf(red[0], red[1]);
  __syncthreads();
  float e = __expf(logit - m);
  float s = e;
  for (int o = 32; o; o >>= 1) s += __shfl_xor(s, o, 64);
  if ((j & 63) == 0) red[wid] = s;
  __syncthreads();
  s = red[0] + red[1];
  Ah[(size_t)j * K + i] = (_Float16)(e / s);  // column-major f16
}

__global__ void k_pi(const float* __restrict__ x, float* __restrict__ pi) {
  int j = threadIdx.x;
  __shared__ float red[2];
  float v = x[j];
  int wid = j >> 6;
  float m = v;
  for (int o = 32; o; o >>= 1) m = fmaxf(m, __shfl_xor(m, o, 64));
  if ((j & 63) == 0) red[wid] = m;
  __syncthreads();
  m = fmaxf(red[0], red[1]);
  __syncthreads();
  float e = __expf(v - m);
  float s = e;
  for (int o = 32; o; o >>= 1) s += __shfl_xor(s, o, 64);
  if ((j & 63) == 0) red[wid] = s;
  __syncthreads();
  s = red[0] + red[1];
  pi[j] = e / (red[0] + red[1]);
}

// 2-wave forward recurrence; A column as 64 pinned scalar dwords (f16 pairs);
// p in LDS as f16; matvec via v_pk_fma_f16; one barrier per step.
__global__ void __launch_bounds__(128, 1) k_forward(
    const int* __restrict__ emis, const float* __restrict__ scoresT,
    const float* __restrict__ lse, const float* __restrict__ mB,
    const _Float16* __restrict__ Ah, const float* __restrict__ pi,
    float* __restrict__ sll) {
  __shared__ __align__(16) _Float16 psB[2][K];
  __shared__ float zbuf[2][2];
  __shared__ float spb[2];
  __shared__ int es[T];
  int b = blockIdx.x;
  int tid = threadIdx.x;  // 0..127
  int w = tid >> 6;       // wave id
  int l = tid & 63;
  int j = tid;            // owned state column
  for (int t = tid; t < T; t += 128) es[t] = emis[b * T + t];
  const unsigned* cp = (const unsigned*)(Ah + (size_t)j * K);  // 256B contiguous column
  unsigned a0  = cp[0],  a1  = cp[1],  a2  = cp[2],  a3  = cp[3];
  unsigned a4  = cp[4],  a5  = cp[5],  a6  = cp[6],  a7  = cp[7];
  unsigned a8  = cp[8],  a9  = cp[9],  a10 = cp[10], a11 = cp[11];
  unsigned a12 = cp[12], a13 = cp[13], a14 = cp[14], a15 = cp[15];
  unsigned a16 = cp[16], a17 = cp[17], a18 = cp[18], a19 = cp[19];
  unsigned a20 = cp[20], a21 = cp[21], a22 = cp[22], a23 = cp[23];
  unsigned a24 = cp[24], a25 = cp[25], a26 = cp[26], a27 = cp[27];
  unsigned a28 = cp[28], a29 = cp[29], a30 = cp[30], a31 = cp[31];
  unsigned a32 = cp[32], a33 = cp[33], a34 = cp[34], a35 = cp[35];
  unsigned a36 = cp[36], a37 = cp[37], a38 = cp[38], a39 = cp[39];
  unsigned a40 = cp[40], a41 = cp[41], a42 = cp[42], a43 = cp[43];
  unsigned a44 = cp[44], a45 = cp[45], a46 = cp[46], a47 = cp[47];
  unsigned a48 = cp[48], a49 = cp[49], a50 = cp[50], a51 = cp[51];
  unsigned a52 = cp[52], a53 = cp[53], a54 = cp[54], a55 = cp[55];
  unsigned a56 = cp[56], a57 = cp[57], a58 = cp[58], a59 = cp[59];
  unsigned a60 = cp[60], a61 = cp[61], a62 = cp[62], a63 = cp[63];
  float lsej = lse[j];
  float pij = pi[j];
  __syncthreads();  // es ready
  // prologue: p0 = pi * exp(s - lse - mB[w0]); max(p0) in [1/128, 1]
  int w0 = es[0];
  float sc0 = scoresT[(size_t)w0 * K + j];
  float mb0 = mB[w0];
  float p = pij * __expf(sc0 - lsej - mb0);
  psB[0][j] = (_Float16)p;
  float zm0 = wave_max63(p);
  if (l == 63) zbuf[0][w] = zm0;
  float Cacc = mb0;
  // emission pipeline (4-deep)
  float scA = scoresT[(size_t)es[1] * K + j];
  float mbA = mB[es[1]];
  float ebA = __expf(scA - lsej - mbA);
  float scB = scoresT[(size_t)es[2] * K + j];
  float mbB = mB[es[2]];
  float scC = scoresT[(size_t)es[3] * K + j];
  float mbC = mB[es[3]];
  int wD = es[4];
  __syncthreads();  // psB[0], zbuf[0] visible
  float pn = p;
  for (int t = 1; t < T; t++) {
    // pin A in arch VGPRs (scalar operands: one register each)
    asm volatile("" : "+v"(a0), "+v"(a1), "+v"(a2), "+v"(a3), "+v"(a4), "+v"(a5),
                      "+v"(a6), "+v"(a7), "+v"(a8), "+v"(a9), "+v"(a10), "+v"(a11),
                      "+v"(a12), "+v"(a13), "+v"(a14), "+v"(a15));
    asm volatile("" : "+v"(a16), "+v"(a17), "+v"(a18), "+v"(a19), "+v"(a20), "+v"(a21),
                      "+v"(a22), "+v"(a23), "+v"(a24), "+v"(a25), "+v"(a26), "+v"(a27),
                      "+v"(a28), "+v"(a29), "+v"(a30), "+v"(a31));
    asm volatile("" : "+v"(a32), "+v"(a33), "+v"(a34), "+v"(a35), "+v"(a36), "+v"(a37),
                      "+v"(a38), "+v"(a39), "+v"(a40), "+v"(a41), "+v"(a42), "+v"(a43),
                      "+v"(a44), "+v"(a45), "+v"(a46), "+v"(a47));
    asm volatile("" : "+v"(a48), "+v"(a49), "+v"(a50), "+v"(a51), "+v"(a52), "+v"(a53),
                      "+v"(a54), "+v"(a55), "+v"(a56), "+v"(a57), "+v"(a58), "+v"(a59),
                      "+v"(a60), "+v"(a61), "+v"(a62), "+v"(a63));
    int cur = (t - 1) & 1, nxt = t & 1;
    // prefetch token t+3
    float scD = scoresT[(size_t)wD * K + j];
    float mbD = mB[wD];
    int wE = es[(t + 4 < T) ? t + 4 : T - 1];
    // rescale factors from previous step's published max (one-step slack)
    float z = fmaxf(fmaxf(zbuf[cur][0], zbuf[cur][1]), 1e-30f);
    float r = __builtin_amdgcn_rcpf(z);
    float lzp = __logf(z);
    float er = ebA * r;
    // matvec: q_j = sum_i p_i * A_ij ; packed f16 FMAs, f16 sub-accumulators
    h2 qa = (h2)0, qb = (h2)0, qc = (h2)0, qd = (h2)0;
    const uint4* pp = (const uint4*)&psB[cur][0];
#define BLK(II, X, Y, Z, W)                                                 \
    {                                                                       \
      uint4 Pd = pp[II];                                                    \
      qa = __builtin_elementwise_fma(h2cast(Pd.x), h2cast(X), qa);          \
      qb = __builtin_elementwise_fma(h2cast(Pd.y), h2cast(Y), qb);          \
      qc = __builtin_elementwise_fma(h2cast(Pd.z), h2cast(Z), qc);          \
      qd = __builtin_elementwise_fma(h2cast(Pd.w), h2cast(W), qd);          \
    }
    BLK(0,  a0,  a1,  a2,  a3)   BLK(1,  a4,  a5,  a6,  a7)
    BLK(2,  a8,  a9,  a10, a11)  BLK(3,  a12, a13, a14, a15)
    BLK(4,  a16, a17, a18, a19)  BLK(5,  a20, a21, a22, a23)
    BLK(6,  a24, a25, a26, a27)  BLK(7,  a28, a29, a30, a31)
    BLK(8,  a32, a33, a34, a35)  BLK(9,  a36, a37, a38, a39)
    BLK(10, a40, a41, a42, a43)  BLK(11, a44, a45, a46, a47)
    BLK(12, a48, a49, a50, a51)  BLK(13, a52, a53, a54, a55)
    BLK(14, a56, a57, a58, a59)  BLK(15, a60, a61, a62, a63)
#undef BLK
    float q = (((float)qa.x + (float)qa.y) + ((float)qb.x + (float)qb.y)) +
              (((float)qc.x + (float)qc.y) + ((float)qd.x + (float)qd.y));
    pn = q * er;
    Cacc += lzp + mbA;
    psB[nxt][j] = (_Float16)pn;
    float zm = wave_max63(pn);
    if (l == 63) zbuf[nxt][w] = zm;
    // advance emission pipeline
    ebA = __expf(scB - lsej - mbB);
    mbA = mbB;
    scB = scC; mbB = mbC;
    scC = scD; mbC = mbD;
    wD = wE;
    __syncthreads();
  }
  // seq_ll = Cacc + log(sum_j p_T[j])
  float sw = wave_sum63(pn);
  if (l == 63) spb[w] = sw;
  __syncthreads();
  if (tid == 0) sll[b] = Cacc + __logf(spb[0] + spb[1]);
}

__global__ void k_loss(const float* __restrict__ sll, float* __restrict__ out) {
  int tid = threadIdx.x;
  __shared__ float red[4];
  float v = sll[tid];
#pragma unroll
  for (int o = 32; o; o >>= 1) v += __shfl_xor(v, o, 64);
  if ((tid & 63) == 0) red[tid >> 6] = v;
  __syncthreads();
  if (tid == 0) out[0] = -(red[0] + red[1] + red[2] + red[3]) / (float)B;
}

extern "C" void kernel_launch(void* const* d_in, const int* in_sizes, int n_in,
                              void* d_out, int out_size, void* d_ws, size_t ws_size,
                              hipStream_t stream) {
  const int*   emis   = (const int*)d_in[0];
  const float* initl  = (const float*)d_in[1];
  const float* tagw   = (const float*)d_in[2];
  const float* wordw  = (const float*)d_in[3];
  const float* wordb  = (const float*)d_in[4];
  const float* transw = (const float*)d_in[5];
  const float* transb = (const float*)d_in[6];
  const float* transq = (const float*)d_in[7];
  float* ws = (float*)d_ws;
  size_t off = 0;
  float* scoresT = ws + off; off += (size_t)V * K;
  _Float16* Ah   = (_Float16*)(ws + off); off += (size_t)K * K / 2;
  float* pivec   = ws + off; off += K;
  float* lse     = ws + off; off += K;
  float* pmax    = ws + off; off += (size_t)NLB * 256;
  float* psum    = ws + off; off += (size_t)NLB * 256;
  float* mB      = ws + off; off += (size_t)V + 64;
  float* sll     = ws + off; off += B;
  float* out = (float*)d_out;

  hipLaunchKernelGGL(k_transA, dim3(K), dim3(K), 0, stream, transw, transb, transq, Ah);
  hipLaunchKernelGGL(k_pi, dim3(1), dim3(K), 0, stream, initl, pivec);
  hipLaunchKernelGGL(k_scores, dim3((V + 255) / 256), dim3(256), 0, stream, tagw, wordw, wordb, scoresT);
  hipLaunchKernelGGL(k_collse, dim3(NLB), dim3(256), 0, stream, scoresT, pmax, psum);
  hipLaunchKernelGGL(k_lsefin, dim3(1), dim3(256), 0, stream, pmax, psum, lse);
  hipLaunchKernelGGL(k_rowmax, dim3((V + 255) / 256), dim3(256), 0, stream, scoresT, lse, mB);
  hipLaunchKernelGGL(k_forward, dim3(B), dim3(128), 0, stream, emis, scoresT, lse, mB, Ah, pivec, sll);
  hipLaunchKernelGGL(k_loss, dim3(1), dim3(256), 0, stream, sll, out);
}

// Round 8
// 908.158 us; speedup vs baseline: 1.8619x; 1.1253x over previous
//
#include <hip/hip_runtime.h>
#include <math.h>

#define K 128
#define V 50257
#define D 128
#define H 128
#define B 256
#define T 1024
#define NLB 256
#define WPB 197   // 256*197 = 50432 >= V

typedef _Float16 h2 __attribute__((ext_vector_type(2)));

__device__ __forceinline__ h2 h2cast(unsigned int u) { return __builtin_bit_cast(h2, u); }

// LDS-only barrier: order LDS ops across waves WITHOUT draining vmcnt
// (keeps global prefetch loads in flight across steps).
__device__ __forceinline__ void lds_barrier() {
  __builtin_amdgcn_sched_barrier(0);
  asm volatile("s_waitcnt lgkmcnt(0)" ::: "memory");
  __builtin_amdgcn_s_barrier();
  __builtin_amdgcn_sched_barrier(0);
}

// ---- DPP wave reduces (result valid in lane 63) ----
__device__ __forceinline__ float wave_max63(float x) {
  int xi;
#define MSTEP(ctrl, rm, bm)                                                          \
  xi = __builtin_amdgcn_update_dpp(__float_as_int(x), __float_as_int(x), ctrl, rm,   \
                                   bm, false);                                       \
  x = fmaxf(x, __int_as_float(xi));
  MSTEP(0x111, 0xf, 0xf)  // row_shr:1
  MSTEP(0x112, 0xf, 0xf)  // row_shr:2
  MSTEP(0x114, 0xf, 0xe)  // row_shr:4
  MSTEP(0x118, 0xf, 0xc)  // row_shr:8
  MSTEP(0x142, 0xa, 0xf)  // row_bcast:15
  MSTEP(0x143, 0xc, 0xf)  // row_bcast:31
#undef MSTEP
  return x;
}
__device__ __forceinline__ float wave_sum63(float x) {
  int xi;
#define SSTEP(ctrl, rm, bm)                                                          \
  xi = __builtin_amdgcn_update_dpp(0, __float_as_int(x), ctrl, rm, bm, true);        \
  x = x + __int_as_float(xi);
  SSTEP(0x111, 0xf, 0xf)
  SSTEP(0x112, 0xf, 0xf)
  SSTEP(0x114, 0xf, 0xe)
  SSTEP(0x118, 0xf, 0xc)
  SSTEP(0x142, 0xa, 0xf)
  SSTEP(0x143, 0xc, 0xf)
#undef SSTEP
  return x;
}

// scoresT[w][k] = dot(tag[k], word[w]) + bias[w]; thread-per-word, tags in LDS
__global__ void __launch_bounds__(256) k_scores(const float* __restrict__ tag_w,
                                                const float* __restrict__ word_w,
                                                const float* __restrict__ word_b,
                                                float* __restrict__ scoresT) {
  __shared__ __align__(16) float tg[K][D];  // 64 KB
  int tid = threadIdx.x;
#pragma unroll
  for (int q = 0; q < 16; q++) {
    int f4 = q * 256 + tid;
    ((float4*)tg)[f4] = ((const float4*)tag_w)[f4];
  }
  __syncthreads();
  int w = blockIdx.x * 256 + tid;
  if (w >= V) return;
  float wb = word_b[w];
  float4 wreg[32];
#pragma unroll
  for (int c = 0; c < 32; c++) wreg[c] = *(const float4*)(word_w + (size_t)w * D + 4 * c);
  for (int k4 = 0; k4 < 32; k4++) {
    float4 out;
    float* op = (float*)&out;
#pragma unroll
    for (int kk = 0; kk < 4; kk++) {
      int k = k4 * 4 + kk;
      float a0 = 0, a1 = 0, a2 = 0, a3 = 0;
#pragma unroll
      for (int c = 0; c < 32; c++) {
        float4 t4 = *(const float4*)&tg[k][4 * c];
        a0 = fmaf(t4.x, wreg[c].x, a0);
        a1 = fmaf(t4.y, wreg[c].y, a1);
        a2 = fmaf(t4.z, wreg[c].z, a2);
        a3 = fmaf(t4.w, wreg[c].w, a3);
      }
      op[kk] = (a0 + a1) + (a2 + a3) + wb;
    }
    *(float4*)&scoresT[(size_t)w * K + 4 * k4] = out;
  }
}

// per-k online (max,sumexp) over a word slice
__global__ void __launch_bounds__(256) k_collse(const float* __restrict__ scoresT,
                                                float* __restrict__ pmax,
                                                float* __restrict__ psum) {
  int tid = threadIdx.x;
  int blk = blockIdx.x;
  int k = tid & 127, half = tid >> 7;
  int w0 = blk * WPB;
  int wend = min(w0 + WPB, V);
  float m = -1e30f, s = 0.f;
  for (int w = w0 + half; w < wend; w += 2) {
    float v = scoresT[(size_t)w * K + k];
    if (v > m) { s *= __expf(m - v); m = v; }
    s += __expf(v - m);
  }
  pmax[blk * 256 + tid] = m;
  psum[blk * 256 + tid] = s;
}

__global__ void k_lsefin(const float* __restrict__ pmax, const float* __restrict__ psum,
                         float* __restrict__ lse) {
  __shared__ float sm[2][K], ss[2][K];
  int tid = threadIdx.x;
  int k = tid & 127, half = tid >> 7;
  float m = -1e30f, s = 0.f;
  for (int blk = 0; blk < NLB; blk++) {
    float pm = pmax[blk * 256 + half * 128 + k];
    float pv = psum[blk * 256 + half * 128 + k];
    float nm = fmaxf(m, pm);
    s = s * __expf(m - nm) + pv * __expf(pm - nm);
    m = nm;
  }
  sm[half][k] = m;
  ss[half][k] = s;
  __syncthreads();
  if (tid < K) {
    float nm = fmaxf(sm[0][tid], sm[1][tid]);
    float st = ss[0][tid] * __expf(sm[0][tid] - nm) + ss[1][tid] * __expf(sm[1][tid] - nm);
    lse[tid] = nm + __logf(st);
  }
}

// mB[w] = max_k (score[w][k] - lse[k])
__global__ void __launch_bounds__(256) k_rowmax(const float* __restrict__ scoresT,
                                                const float* __restrict__ lse,
                                                float* __restrict__ mB) {
  __shared__ __align__(16) float ls[K];
  int tid = threadIdx.x;
  if (tid < K) ls[tid] = lse[tid];
  __syncthreads();
  int w = blockIdx.x * 256 + tid;
  if (w >= V) return;
  const float* row = scoresT + (size_t)w * K;
  float mx = -1e30f;
#pragma unroll
  for (int c = 0; c < 32; c++) {
    float4 s4 = *(const float4*)&row[4 * c];
    float4 l4 = *(const float4*)&ls[4 * c];
    mx = fmaxf(mx, fmaxf(fmaxf(s4.x - l4.x, s4.y - l4.y), fmaxf(s4.z - l4.z, s4.w - l4.w)));
  }
  mB[w] = mx;
}

// Ah[j][i] (column-major, f16): softmax over j of row i
__global__ void k_transA(const float* __restrict__ trans_w, const float* __restrict__ trans_b,
                         const float* __restrict__ trans_q, _Float16* __restrict__ Ah) {
  __shared__ __align__(16) float qs[H];
  __shared__ float red[2];
  int i = blockIdx.x;
  int j = threadIdx.x;
  qs[j] = trans_q[j];
  __syncthreads();
  const float* wrow = trans_w + (size_t)(i * K + j) * H;
  float acc = 0.f;
#pragma unroll
  for (int h = 0; h < H; h += 4) {
    float4 w4 = *(const float4*)(wrow + h);
    float4 q4 = *(const float4*)(qs + h);
    acc += w4.x * q4.x + w4.y * q4.y + w4.z * q4.z + w4.w * q4.w;
  }
  float logit = acc + trans_b[i * K + j];
  int wid = j >> 6;
  float m = logit;
  for (int o = 32; o; o >>= 1) m = fmaxf(m, __shfl_xor(m, o, 64));
  if ((j & 63) == 0) red[wid] = m;
  __syncthreads();
  m = fmaxf(red[0], red[1]);
  __syncthreads();
  float e = __expf(logit - m);
  float s = e;
  for (int o = 32; o; o >>= 1) s += __shfl_xor(s, o, 64);
  if ((j & 63) == 0) red[wid] = s;
  __syncthreads();
  s = red[0] + red[1];
  Ah[(size_t)j * K + i] = (_Float16)(e / s);  // column-major f16
}

__global__ void k_pi(const float* __restrict__ x, float* __restrict__ pi) {
  int j = threadIdx.x;
  __shared__ float red[2];
  float v = x[j];
  int wid = j >> 6;
  float m = v;
  for (int o = 32; o; o >>= 1) m = fmaxf(m, __shfl_xor(m, o, 64));
  if ((j & 63) == 0) red[wid] = m;
  __syncthreads();
  m = fmaxf(red[0], red[1]);
  __syncthreads();
  float e = __expf(v - m);
  float s = e;
  for (int o = 32; o; o >>= 1) s += __shfl_xor(s, o, 64);
  if ((j & 63) == 0) red[wid] = s;
  __syncthreads();
  s = red[0] + red[1];
  pi[j] = e / (red[0] + red[1]);
}

// 2-wave forward recurrence; A (f16) in LDS with XOR-swizzled columns;
// p in LDS as f16 (double-buffered); matvec via v_pk_fma_f16;
// one LDS-only barrier per step (global prefetches never drained).
__global__ void __launch_bounds__(128, 1) k_forward(
    const int* __restrict__ emis, const float* __restrict__ scoresT,
    const float* __restrict__ lse, const float* __restrict__ mB,
    const _Float16* __restrict__ Ah, const float* __restrict__ pi,
    float* __restrict__ sll) {
  __shared__ __align__(16) _Float16 Alds[K * K];  // 32 KB, swizzled col-major
  __shared__ __align__(16) _Float16 psB[2][K];
  __shared__ float zbuf[2][2];
  __shared__ float spb[2];
  __shared__ int es[T];
  int b = blockIdx.x;
  int tid = threadIdx.x;  // 0..127
  int w = tid >> 6;       // wave id
  int l = tid & 63;
  int j = tid;            // owned state column
  for (int t = tid; t < T; t += 128) es[t] = emis[b * T + t];
  // stage A into LDS with 16B-unit XOR swizzle: unit u of column j -> slot (u ^ (j&15))
  for (int idx = tid; idx < K * 16; idx += 128) {
    int jj = idx >> 4, uu = idx & 15;
    ((uint4*)Alds)[jj * 16 + (uu ^ (jj & 15))] = ((const uint4*)Ah)[idx];
  }
  float lsej = lse[j];
  float pij = pi[j];
  __syncthreads();  // es + Alds ready
  // prologue: p0 = pi * exp(s - lse - mB[w0]); max(p0) in [1/128, 1]
  int w0 = es[0];
  float sc0 = scoresT[(size_t)w0 * K + j];
  float mb0 = mB[w0];
  float p = pij * __expf(sc0 - lsej - mb0);
  psB[0][j] = (_Float16)p;
  float zm0 = wave_max63(p);
  if (l == 63) zbuf[0][w] = zm0;
  float Cacc = mb0;
  // emission pipeline (4-deep)
  float scA = scoresT[(size_t)es[1] * K + j];
  float mbA = mB[es[1]];
  float ebA = __expf(scA - lsej - mbA);
  float scB = scoresT[(size_t)es[2] * K + j];
  float mbB = mB[es[2]];
  float scC = scoresT[(size_t)es[3] * K + j];
  float mbC = mB[es[3]];
  int wD = es[4];
  __syncthreads();  // psB[0], zbuf[0] visible
  const char* Acol_base = (const char*)&Alds[(size_t)j * K];  // j*256 bytes
  unsigned sw16 = ((unsigned)(j & 15)) << 4;
  float pn = p;
  for (int t = 1; t < T; t++) {
    int cur = (t - 1) & 1, nxt = t & 1;
    // prefetch token t+3 (stays in flight across the lgkm-only barrier)
    float scD = scoresT[(size_t)wD * K + j];
    float mbD = mB[wD];
    int wE = es[(t + 4 < T) ? t + 4 : T - 1];
    // rescale factors from previous step's published max (one-step slack)
    float z = fmaxf(fmaxf(zbuf[cur][0], zbuf[cur][1]), 1e-30f);
    float r = __builtin_amdgcn_rcpf(z);
    float lzp = __logf(z);
    float er = ebA * r;
    // matvec: q_j = sum_i p_i * A_ij ; A column from swizzled LDS, p broadcast
    h2 qa = (h2)0, qb = (h2)0, qc = (h2)0, qd = (h2)0;
    const uint4* pp = (const uint4*)&psB[cur][0];
#pragma unroll
    for (int u = 0; u < 16; u++) {
      uint4 Au = *(const uint4*)(Acol_base + ((((unsigned)u << 4) ^ sw16)));
      uint4 Pd = pp[u];
      qa = __builtin_elementwise_fma(h2cast(Pd.x), h2cast(Au.x), qa);
      qb = __builtin_elementwise_fma(h2cast(Pd.y), h2cast(Au.y), qb);
      qc = __builtin_elementwise_fma(h2cast(Pd.z), h2cast(Au.z), qc);
      qd = __builtin_elementwise_fma(h2cast(Pd.w), h2cast(Au.w), qd);
    }
    float q = (((float)qa.x + (float)qa.y) + ((float)qb.x + (float)qb.y)) +
              (((float)qc.x + (float)qc.y) + ((float)qd.x + (float)qd.y));
    pn = q * er;
    Cacc += lzp + mbA;
    psB[nxt][j] = (_Float16)pn;
    float zm = wave_max63(pn);
    if (l == 63) zbuf[nxt][w] = zm;
    // advance emission pipeline
    ebA = __expf(scB - lsej - mbB);
    mbA = mbB;
    scB = scC; mbB = mbC;
    scC = scD; mbC = mbD;
    wD = wE;
    lds_barrier();
  }
  // seq_ll = Cacc + log(sum_j p_T[j])
  float sw = wave_sum63(pn);
  if (l == 63) spb[w] = sw;
  __syncthreads();
  if (tid == 0) sll[b] = Cacc + __logf(spb[0] + spb[1]);
}

__global__ void k_loss(const float* __restrict__ sll, float* __restrict__ out) {
  int tid = threadIdx.x;
  __shared__ float red[4];
  float v = sll[tid];
#pragma unroll
  for (int o = 32; o; o >>= 1) v += __shfl_xor(v, o, 64);
  if ((tid & 63) == 0) red[tid >> 6] = v;
  __syncthreads();
  if (tid == 0) out[0] = -(red[0] + red[1] + red[2] + red[3]) / (float)B;
}

extern "C" void kernel_launch(void* const* d_in, const int* in_sizes, int n_in,
                              void* d_out, int out_size, void* d_ws, size_t ws_size,
                              hipStream_t stream) {
  const int*   emis   = (const int*)d_in[0];
  const float* initl  = (const float*)d_in[1];
  const float* tagw   = (const float*)d_in[2];
  const float* wordw  = (const float*)d_in[3];
  const float* wordb  = (const float*)d_in[4];
  const float* transw = (const float*)d_in[5];
  const float* transb = (const float*)d_in[6];
  const float* transq = (const float*)d_in[7];
  float* ws = (float*)d_ws;
  size_t off = 0;
  float* scoresT = ws + off; off += (size_t)V * K;
  _Float16* Ah   = (_Float16*)(ws + off); off += (size_t)K * K / 2;
  float* pivec   = ws + off; off += K;
  float* lse     = ws + off; off += K;
  float* pmax    = ws + off; off += (size_t)NLB * 256;
  float* psum    = ws + off; off += (size_t)NLB * 256;
  float* mB      = ws + off; off += (size_t)V + 64;
  float* sll     = ws + off; off += B;
  float* out = (float*)d_out;

  hipLaunchKernelGGL(k_transA, dim3(K), dim3(K), 0, stream, transw, transb, transq, Ah);
  hipLaunchKernelGGL(k_pi, dim3(1), dim3(K), 0, stream, initl, pivec);
  hipLaunchKernelGGL(k_scores, dim3((V + 255) / 256), dim3(256), 0, stream, tagw, wordw, wordb, scoresT);
  hipLaunchKernelGGL(k_collse, dim3(NLB), dim3(256), 0, stream, scoresT, pmax, psum);
  hipLaunchKernelGGL(k_lsefin, dim3(1), dim3(256), 0, stream, pmax, psum, lse);
  hipLaunchKernelGGL(k_rowmax, dim3((V + 255) / 256), dim3(256), 0, stream, scoresT, lse, mB);
  hipLaunchKernelGGL(k_forward, dim3(B), dim3(128), 0, stream, emis, scoresT, lse, mB, Ah, pivec, sll);
  hipLaunchKernelGGL(k_loss, dim3(1), dim3(256), 0, stream, sll, out);
}